// Round 1
// 6793.089 us; speedup vs baseline: 1.1283x; 1.1283x over previous
//
#include <hip/hip_runtime.h>

// LSTM S=512,B=128,I=H=1024. Round 3: vectorized (f32x4) K-split reduction
// epilogue + 2-deep K-loop prefetch + hoisted bias/c loads.
// gates_t = [h_t | x_t] @ [w_hh | w_ih]^T + bias  (K=2048, bf16 MFMA, fp32 acc)

#define S_LEN 512

using short8 = __attribute__((ext_vector_type(8))) short;  // 8 bf16 = one frag
using f32x4  = __attribute__((ext_vector_type(4))) float;

__device__ __forceinline__ unsigned short f2bf(float f) {
  unsigned int u = __float_as_uint(f);
  u += 0x7fffu + ((u >> 16) & 1u);   // RNE
  return (unsigned short)(u >> 16);
}
__device__ __forceinline__ unsigned int pk2(float a, float b) {
  return (unsigned int)f2bf(a) | ((unsigned int)f2bf(b) << 16);
}
__device__ __forceinline__ float sigf(float x)  { return 1.f / (1.f + __expf(-x)); }
__device__ __forceinline__ float tanhf_(float x){ return 2.f / (1.f + __expf(-2.f * x)) - 1.f; }

// ---- pack x: xp[t][rh2][kq4][ks8][rf4][ln64][8]  (a-frag order, bf16) ----
// a-frag mapping (16x16x32): row=lane&15, k=(lane>>4)*8+e
__global__ void xpack_kernel(const float* __restrict__ x, unsigned short* __restrict__ xp) {
  const int gid = blockIdx.x * 256 + threadIdx.x;     // 8,388,608 total
  const int t  = gid >> 14;
  const int u  = gid & 16383;
  const int ln = u & 63;
  const int u6 = u >> 6;            // (((rh*4+kq)*8+ks)*4+rf)
  const int rf = u6 & 3;
  const int ks = (u6 >> 2) & 7;
  const int kq = (u6 >> 5) & 3;
  const int rh = u6 >> 7;
  const int row = rh * 64 + rf * 16 + (ln & 15);
  const int i   = kq * 256 + ks * 32 + (ln >> 4) * 8;
  const float* src = x + ((size_t)t * 131072 + (size_t)row * 1024 + i);
  const float4 v0 = *(const float4*)src;
  const float4 v1 = *(const float4*)(src + 4);
  uint4 o;
  o.x = pk2(v0.x, v0.y); o.y = pk2(v0.z, v0.w);
  o.z = pk2(v1.x, v1.y); o.w = pk2(v1.z, v1.w);
  *(uint4*)(xp + (size_t)gid * 8) = o;
}

// ---- pack weights: wp[b64][kq8][ks8][cg4][ln64][8]  (b-frag order) ----
// fused K: kq<4 -> w_hh[k = kq*256+...], kq>=4 -> w_ih[k-1024]
__global__ void wpack_kernel(const float* __restrict__ w_hh, const float* __restrict__ w_ih,
                             unsigned short* __restrict__ wp) {
  const int gid = blockIdx.x * 256 + threadIdx.x;     // 1,048,576 total
  const int ln = gid & 63;
  const int u6 = gid >> 6;          // (((b*8+kq)*8+ks)*4+cg)
  const int cg = u6 & 3;
  const int ks = (u6 >> 2) & 7;
  const int kq = (u6 >> 5) & 7;
  const int b  = u6 >> 8;
  const int grow = cg * 1024 + b * 16 + (ln & 15);    // gate row
  const int k    = kq * 256 + ks * 32 + (ln >> 4) * 8;
  const float* src = (k < 1024) ? (w_hh + (size_t)grow * 1024 + k)
                                : (w_ih + (size_t)grow * 1024 + (k - 1024));
  const float4 v0 = *(const float4*)src;
  const float4 v1 = *(const float4*)(src + 4);
  uint4 o;
  o.x = pk2(v0.x, v0.y); o.y = pk2(v0.z, v0.w);
  o.z = pk2(v1.x, v1.y); o.w = pk2(v1.z, v1.w);
  *(uint4*)(wp + (size_t)gid * 8) = o;
}

__global__ void bias_sum_kernel(const float* __restrict__ a, const float* __restrict__ b,
                                float* __restrict__ o, int n) {
  int i = blockIdx.x * blockDim.x + threadIdx.x;
  if (i < n) o[i] = a[i] + b[i];
}

// ---- one LSTM step ----
// grid 128: block = (b = bid>>1 -> h-cols [16b,16b+16) x 4 gates, rh = bid&1 -> rows [64rh,64rh+64))
// 8 waves = 8-way K-split (256 K each); wave tile [64 rows x 64 gate-cols], acc 16 f32x4.
// Epilogue: f32x4 partials through LDS (ds_write_b128 / ds_read_b128, conflict-free),
// 2 gate-pair passes within a 64 KB buffer, fused activation once per cell.
__global__ __launch_bounds__(512) void lstm_step(
    const unsigned short* __restrict__ hp_in,   // packed h  [rh2][kq4][ks8][rf4][ln64][8]
    const unsigned short* __restrict__ xp_t,    // packed x_t, same shape
    const unsigned short* __restrict__ wp,      // packed weights
    const float* __restrict__ bias,             // [4096]
    float* __restrict__ cbuf,                   // [128][1024] fp32
    float* __restrict__ out_t,                  // [128][1024] fp32
    unsigned short* __restrict__ hp_out)        // packed next h
{
  __shared__ f32x4 P[8][4][2][64];   // 64 KB: [kq][rf][gate-pair][lane]
  const int tid  = threadIdx.x;
  const int lane = tid & 63;
  const int w    = tid >> 6;       // wave = kq 0..7
  const int b    = blockIdx.x >> 1;
  const int rh   = blockIdx.x & 1;

  const unsigned short* ab = (w < 4) ? (hp_in + (size_t)(rh * 4 + w) * 16384)
                                     : (xp_t  + (size_t)(rh * 4 + (w - 4)) * 16384);
  const unsigned short* bb = wp + (size_t)(b * 8 + w) * 16384;

  // ---- hoisted epilogue state (reader threads = tid<256) ----
  // reader mapping: rf_r = tid>>6 (= wave id), q_r = (tid>>4)&3, c15r = tid&15
  // covers rows row0..row0+3 (r) for h-col j; 256 threads x 4 rows = all 1024 cells.
  const int rf_r = tid >> 6;
  const int q_r  = (tid >> 4) & 3;
  const int c15r = tid & 15;
  const int j    = b * 16 + c15r;
  const int row0 = rh * 64 + rf_r * 16 + q_r * 4;
  float b0 = 0.f, b1 = 0.f, b2 = 0.f, b3 = 0.f;
  float cold[4] = {0.f, 0.f, 0.f, 0.f};
  if (tid < 256) {
    b0 = bias[j]; b1 = bias[1024 + j]; b2 = bias[2048 + j]; b3 = bias[3072 + j];
#pragma unroll
    for (int r = 0; r < 4; ++r) cold[r] = cbuf[(size_t)(row0 + r) * 1024 + j];
  }

  // ---- K-loop: 2-deep prefetch, 3-buffer rotation (fully unrolled => static idx) ----
  short8 afr[3][4], bfr[3][4];
#pragma unroll
  for (int p = 0; p < 2; ++p) {
#pragma unroll
    for (int rf = 0; rf < 4; ++rf) afr[p][rf] = *(const short8*)(ab + (p * 4 + rf) * 512 + lane * 8);
#pragma unroll
    for (int cg = 0; cg < 4; ++cg) bfr[p][cg] = *(const short8*)(bb + (p * 4 + cg) * 512 + lane * 8);
  }

  f32x4 acc[4][4] = {};
#pragma unroll
  for (int ks = 0; ks < 8; ++ks) {
    const int cur = ks % 3;
    if (ks < 6) {
      const int nxt = (ks + 2) % 3;
#pragma unroll
      for (int rf = 0; rf < 4; ++rf)
        afr[nxt][rf] = *(const short8*)(ab + ((ks + 2) * 4 + rf) * 512 + lane * 8);
#pragma unroll
      for (int cg = 0; cg < 4; ++cg)
        bfr[nxt][cg] = *(const short8*)(bb + ((ks + 2) * 4 + cg) * 512 + lane * 8);
    }
#pragma unroll
    for (int rf = 0; rf < 4; ++rf)
#pragma unroll
      for (int cg = 0; cg < 4; ++cg)
        acc[rf][cg] = __builtin_amdgcn_mfma_f32_16x16x32_bf16(afr[cur][rf], bfr[cur][cg], acc[rf][cg], 0, 0, 0);
  }

  // ---- vectorized 8-way reduction: 2 passes (gates {0,1} then {2,3}) ----
  // C/D layout: col = lane&15 (gate col), row = (lane>>4)*4 + reg
  f32x4 g0 = {}, g1 = {}, g2 = {}, g3 = {};
#pragma unroll
  for (int pass = 0; pass < 2; ++pass) {
    if (pass) __syncthreads();           // pass-0 reads done before overwrite
#pragma unroll
    for (int rf = 0; rf < 4; ++rf) {
      P[w][rf][0][lane] = acc[rf][pass * 2 + 0];
      P[w][rf][1][lane] = acc[rf][pass * 2 + 1];
    }
    __syncthreads();
    if (tid < 256) {
      // lane == tid&63, reading wave rf_r: contiguous 1KB per ds_read_b128
      f32x4 sa = P[0][rf_r][0][lane];
      f32x4 sb = P[0][rf_r][1][lane];
#pragma unroll
      for (int kq = 1; kq < 8; ++kq) {
        sa += P[kq][rf_r][0][lane];
        sb += P[kq][rf_r][1][lane];
      }
      if (pass == 0) { g0 = sa; g1 = sb; } else { g2 = sa; g3 = sb; }
    }
  }

  // ---- fused activation + state update (one cell per (thread,r)) ----
  if (tid < 256) {
    const int kqm = j >> 8, ksj = (j >> 5) & 7, qj = (j >> 3) & 3, ej = j & 7;
#pragma unroll
    for (int r = 0; r < 4; ++r) {
      const float iv = sigf(g0[r] + b0);
      const float fv = sigf(g1[r] + b1);
      const float gv = tanhf_(g2[r] + b2);
      const float ov = sigf(g3[r] + b3);
      const float cc = fv * cold[r] + iv * gv;
      const int row = row0 + r;
      const size_t idx = (size_t)row * 1024 + j;
      cbuf[idx] = cc;
      const float hh = ov * tanhf_(cc);
      out_t[idx] = hh;
      // write next h in packed a-frag order (row>>6 == rh)
      const int rfj = (row >> 4) & 3, rj = row & 15;
      hp_out[(size_t)((((rh * 4 + kqm) * 8 + ksj) * 4 + rfj) * 64 + (qj * 16 + rj)) * 8 + ej] = f2bf(hh);
    }
  }
}

extern "C" void kernel_launch(void* const* d_in, const int* in_sizes, int n_in,
                              void* d_out, int out_size, void* d_ws, size_t ws_size,
                              hipStream_t stream) {
  (void)in_sizes; (void)n_in; (void)out_size; (void)ws_size;
  const float* x    = (const float*)d_in[0];
  const float* w_ih = (const float*)d_in[1];
  const float* w_hh = (const float*)d_in[2];
  const float* b_ih = (const float*)d_in[3];
  const float* b_hh = (const float*)d_in[4];
  float* out = (float*)d_out;

  char* ws = (char*)d_ws;
  const size_t XP_OFF   = 0;                        // 512*131072*2  = 134217728
  const size_t WP_OFF   = XP_OFF + 134217728;       // 1048576*16    =  16777216
  const size_t BIAS_OFF = WP_OFF + 16777216;        // 16384
  const size_t C_OFF    = BIAS_OFF + 16384;         // 524288
  const size_t H0_OFF   = C_OFF + 524288;           // 262144
  const size_t H1_OFF   = H0_OFF + 262144;          // 262144   (total ~152 MB)

  unsigned short* xp   = (unsigned short*)(ws + XP_OFF);
  unsigned short* wp   = (unsigned short*)(ws + WP_OFF);
  float*          bias = (float*)(ws + BIAS_OFF);
  float*          cbuf = (float*)(ws + C_OFF);
  unsigned short* h0   = (unsigned short*)(ws + H0_OFF);
  unsigned short* h1   = (unsigned short*)(ws + H1_OFF);

  xpack_kernel<<<32768, 256, 0, stream>>>(x, xp);
  wpack_kernel<<<4096, 256, 0, stream>>>(w_hh, w_ih, wp);
  bias_sum_kernel<<<16, 256, 0, stream>>>(b_ih, b_hh, bias, 4096);
  hipMemsetAsync(cbuf, 0, 524288, stream);
  hipMemsetAsync(h0, 0, 262144, stream);

  unsigned short* hin = h0;
  unsigned short* hout = h1;
  for (int t = 0; t < S_LEN; ++t) {
    lstm_step<<<128, 512, 0, stream>>>(hin, xp + (size_t)t * 131072, wp, bias, cbuf,
                                       out + (size_t)t * 131072, hout);
    unsigned short* tmp = hin; hin = hout; hout = tmp;
  }

  // outputs: [S,B,H] | hN | cN
  hipMemcpyAsync(out + (size_t)S_LEN * 131072, out + (size_t)(S_LEN - 1) * 131072,
                 131072 * sizeof(float), hipMemcpyDeviceToDevice, stream);
  hipMemcpyAsync(out + (size_t)S_LEN * 131072 + 131072, cbuf,
                 131072 * sizeof(float), hipMemcpyDeviceToDevice, stream);
}

// Round 2
// 4977.909 us; speedup vs baseline: 1.5397x; 1.3646x over previous
//
#include <hip/hip_runtime.h>

// LSTM S=512,B=128,I=H=1024. Round 4: full-chip grid (256 blocks, 4-way row
// split), single-pass vectorized reduction epilogue, one cell per thread.
// gates_t = [h_t | x_t] @ [w_hh | w_ih]^T + bias  (K=2048, bf16 MFMA, fp32 acc)

#define S_LEN 512

using short8 = __attribute__((ext_vector_type(8))) short;  // 8 bf16 = one frag
using f32x4  = __attribute__((ext_vector_type(4))) float;

__device__ __forceinline__ unsigned short f2bf(float f) {
  unsigned int u = __float_as_uint(f);
  u += 0x7fffu + ((u >> 16) & 1u);   // RNE
  return (unsigned short)(u >> 16);
}
__device__ __forceinline__ unsigned int pk2(float a, float b) {
  return (unsigned int)f2bf(a) | ((unsigned int)f2bf(b) << 16);
}
__device__ __forceinline__ float sigf(float x)  { return 1.f / (1.f + __expf(-x)); }
__device__ __forceinline__ float tanhf_(float x){ return 2.f / (1.f + __expf(-2.f * x)) - 1.f; }

// ---- pack x: xp[t][rh2][kq4][ks8][rf4][ln64][8]  (a-frag order, bf16) ----
// a-frag mapping (16x16x32): row=lane&15, k=(lane>>4)*8+e
__global__ void xpack_kernel(const float* __restrict__ x, unsigned short* __restrict__ xp) {
  const int gid = blockIdx.x * 256 + threadIdx.x;     // 8,388,608 total
  const int t  = gid >> 14;
  const int u  = gid & 16383;
  const int ln = u & 63;
  const int u6 = u >> 6;            // (((rh*4+kq)*8+ks)*4+rf)
  const int rf = u6 & 3;
  const int ks = (u6 >> 2) & 7;
  const int kq = (u6 >> 5) & 3;
  const int rh = u6 >> 7;
  const int row = rh * 64 + rf * 16 + (ln & 15);
  const int i   = kq * 256 + ks * 32 + (ln >> 4) * 8;
  const float* src = x + ((size_t)t * 131072 + (size_t)row * 1024 + i);
  const float4 v0 = *(const float4*)src;
  const float4 v1 = *(const float4*)(src + 4);
  uint4 o;
  o.x = pk2(v0.x, v0.y); o.y = pk2(v0.z, v0.w);
  o.z = pk2(v1.x, v1.y); o.w = pk2(v1.z, v1.w);
  *(uint4*)(xp + (size_t)gid * 8) = o;
}

// ---- pack weights: wp[b64][kq8][ks8][cg4][ln64][8]  (b-frag order) ----
// fused K: kq<4 -> w_hh[k = kq*256+...], kq>=4 -> w_ih[k-1024]
__global__ void wpack_kernel(const float* __restrict__ w_hh, const float* __restrict__ w_ih,
                             unsigned short* __restrict__ wp) {
  const int gid = blockIdx.x * 256 + threadIdx.x;     // 1,048,576 total
  const int ln = gid & 63;
  const int u6 = gid >> 6;          // (((b*8+kq)*8+ks)*4+cg)
  const int cg = u6 & 3;
  const int ks = (u6 >> 2) & 7;
  const int kq = (u6 >> 5) & 7;
  const int b  = u6 >> 8;
  const int grow = cg * 1024 + b * 16 + (ln & 15);    // gate row
  const int k    = kq * 256 + ks * 32 + (ln >> 4) * 8;
  const float* src = (k < 1024) ? (w_hh + (size_t)grow * 1024 + k)
                                : (w_ih + (size_t)grow * 1024 + (k - 1024));
  const float4 v0 = *(const float4*)src;
  const float4 v1 = *(const float4*)(src + 4);
  uint4 o;
  o.x = pk2(v0.x, v0.y); o.y = pk2(v0.z, v0.w);
  o.z = pk2(v1.x, v1.y); o.w = pk2(v1.z, v1.w);
  *(uint4*)(wp + (size_t)gid * 8) = o;
}

__global__ void bias_sum_kernel(const float* __restrict__ a, const float* __restrict__ b,
                                float* __restrict__ o, int n) {
  int i = blockIdx.x * blockDim.x + threadIdx.x;
  if (i < n) o[i] = a[i] + b[i];
}

// ---- one LSTM step ----
// grid 256: bid = rq*64 + b.  b -> h-cols [16b,16b+16) x 4 gates (64 gate-cols),
// rq -> batch rows [32rq, 32rq+32).  Same-b blocks land on the same XCD (b = bid%64
// fixes bid%8) so the 256 KB weight panel is L2-local and reused by 4 row-quarters.
// 8 waves = 8-way K-split (256 K each); wave tile [32 rows x 64 gate-cols],
// acc[2 rf][4 cg].  Single-pass f32x4 LDS reduction, one output cell per thread.
__global__ __launch_bounds__(512) void lstm_step(
    const unsigned short* __restrict__ hp_in,   // packed h  [rh2][kq4][ks8][rf4][ln64][8]
    const unsigned short* __restrict__ xp_t,    // packed x_t, same shape
    const unsigned short* __restrict__ wp,      // packed weights
    const float* __restrict__ bias,             // [4096]
    float* __restrict__ cbuf,                   // [128][1024] fp32
    float* __restrict__ out_t,                  // [128][1024] fp32
    unsigned short* __restrict__ hp_out)        // packed next h
{
  __shared__ f32x4 P[8][2][4][64];   // 64 KB: [kq][rf-frag][gate][lane]
  __shared__ f32x4 G[2][4][64];      // 8 KB: reduced gates
  const int tid  = threadIdx.x;
  const int lane = tid & 63;
  const int w    = tid >> 6;         // wave = kq 0..7
  const int rq   = blockIdx.x >> 6;  // row quarter 0..3
  const int b    = blockIdx.x & 63;  // h-col group
  const int rh   = rq >> 1;          // packed row-half
  const int rfb  = (rq & 1) * 2;     // rf base within the half

  const unsigned short* ab = ((w < 4) ? hp_in : xp_t) + (size_t)(rh * 4 + (w & 3)) * 16384;
  const unsigned short* bb = wp + (size_t)(b * 8 + w) * 16384;

  // ---- per-thread output cell (activation mapping), hoisted loads ----
  // tid = fr*256 + qc*64 + rc*16 + hc ; cell row = rq*32 + fr*16 + qc*4 + rc, col j = b*16+hc
  const int fr = tid >> 8;
  const int qc = (tid >> 6) & 3;
  const int rc = (tid >> 4) & 3;
  const int hc = tid & 15;
  const int j   = b * 16 + hc;
  const int row = rq * 32 + fr * 16 + qc * 4 + rc;
  const size_t idx = (size_t)row * 1024 + j;
  const float b0 = bias[j];
  const float b1 = bias[1024 + j];
  const float b2 = bias[2048 + j];
  const float b3 = bias[3072 + j];
  const float cold = cbuf[idx];

  // ---- K-loop: 2-deep prefetch, 3-buffer rotation (fully unrolled => static idx) ----
  short8 afr[3][2], bfr[3][4];
#pragma unroll
  for (int p = 0; p < 2; ++p) {
#pragma unroll
    for (int f = 0; f < 2; ++f) afr[p][f] = *(const short8*)(ab + (p * 4 + rfb + f) * 512 + lane * 8);
#pragma unroll
    for (int cg = 0; cg < 4; ++cg) bfr[p][cg] = *(const short8*)(bb + (p * 4 + cg) * 512 + lane * 8);
  }

  f32x4 acc[2][4] = {};
#pragma unroll
  for (int ks = 0; ks < 8; ++ks) {
    const int cur = ks % 3;
    if (ks < 6) {
      const int nxt = (ks + 2) % 3;
#pragma unroll
      for (int f = 0; f < 2; ++f)
        afr[nxt][f] = *(const short8*)(ab + ((ks + 2) * 4 + rfb + f) * 512 + lane * 8);
#pragma unroll
      for (int cg = 0; cg < 4; ++cg)
        bfr[nxt][cg] = *(const short8*)(bb + ((ks + 2) * 4 + cg) * 512 + lane * 8);
    }
#pragma unroll
    for (int f = 0; f < 2; ++f)
#pragma unroll
      for (int cg = 0; cg < 4; ++cg)
        acc[f][cg] = __builtin_amdgcn_mfma_f32_16x16x32_bf16(afr[cur][f], bfr[cur][cg], acc[f][cg], 0, 0, 0);
  }

  // ---- single-pass 8-way K reduction (all f32x4, conflict-free) ----
  // C/D layout: col = lane&15 (h-col), gate = cg, rows = frag f: f*16 + (lane>>4)*4 + reg
#pragma unroll
  for (int f = 0; f < 2; ++f)
#pragma unroll
    for (int cg = 0; cg < 4; ++cg)
      P[w][f][cg][lane] = acc[f][cg];
  __syncthreads();
  {
    const int rf_e = w >> 2;      // 0..1
    const int cg_e = w & 3;       // 0..3
    f32x4 s = P[0][rf_e][cg_e][lane];
#pragma unroll
    for (int kq = 1; kq < 8; ++kq) s += P[kq][rf_e][cg_e][lane];
    G[rf_e][cg_e][lane] = s;
  }
  __syncthreads();

  // ---- fused activation + state update: one cell per thread ----
  const float* Gp = (const float*)G;
  const int gbase = (fr * 4) * 256 + (qc * 16 + hc) * 4 + rc;   // float index, cg stride 256
  const float g0 = Gp[gbase];
  const float g1 = Gp[gbase + 256];
  const float g2 = Gp[gbase + 512];
  const float g3 = Gp[gbase + 768];

  const float iv = sigf(g0 + b0);
  const float fv = sigf(g1 + b1);
  const float gv = tanhf_(g2 + b2);
  const float ov = sigf(g3 + b3);
  const float cc = fv * cold + iv * gv;
  cbuf[idx] = cc;
  const float hh = ov * tanhf_(cc);
  out_t[idx] = hh;
  // write next h in packed a-frag order
  const int kqm = j >> 8, ksj = (j >> 5) & 7, qj = (j >> 3) & 3, ej = j & 7;
  const int rhj = row >> 6, rfj = (row >> 4) & 3, rj = row & 15;
  hp_out[(size_t)((((rhj * 4 + kqm) * 8 + ksj) * 4 + rfj) * 64 + (qj * 16 + rj)) * 8 + ej] = f2bf(hh);
}

extern "C" void kernel_launch(void* const* d_in, const int* in_sizes, int n_in,
                              void* d_out, int out_size, void* d_ws, size_t ws_size,
                              hipStream_t stream) {
  (void)in_sizes; (void)n_in; (void)out_size; (void)ws_size;
  const float* x    = (const float*)d_in[0];
  const float* w_ih = (const float*)d_in[1];
  const float* w_hh = (const float*)d_in[2];
  const float* b_ih = (const float*)d_in[3];
  const float* b_hh = (const float*)d_in[4];
  float* out = (float*)d_out;

  char* ws = (char*)d_ws;
  const size_t XP_OFF   = 0;                        // 512*131072*2  = 134217728
  const size_t WP_OFF   = XP_OFF + 134217728;       // 1048576*16    =  16777216
  const size_t BIAS_OFF = WP_OFF + 16777216;        // 16384
  const size_t C_OFF    = BIAS_OFF + 16384;         // 524288
  const size_t H0_OFF   = C_OFF + 524288;           // 262144
  const size_t H1_OFF   = H0_OFF + 262144;          // 262144   (total ~152 MB)

  unsigned short* xp   = (unsigned short*)(ws + XP_OFF);
  unsigned short* wp   = (unsigned short*)(ws + WP_OFF);
  float*          bias = (float*)(ws + BIAS_OFF);
  float*          cbuf = (float*)(ws + C_OFF);
  unsigned short* h0   = (unsigned short*)(ws + H0_OFF);
  unsigned short* h1   = (unsigned short*)(ws + H1_OFF);

  xpack_kernel<<<32768, 256, 0, stream>>>(x, xp);
  wpack_kernel<<<4096, 256, 0, stream>>>(w_hh, w_ih, wp);
  bias_sum_kernel<<<16, 256, 0, stream>>>(b_ih, b_hh, bias, 4096);
  hipMemsetAsync(cbuf, 0, 524288, stream);
  hipMemsetAsync(h0, 0, 262144, stream);

  unsigned short* hin = h0;
  unsigned short* hout = h1;
  for (int t = 0; t < S_LEN; ++t) {
    lstm_step<<<256, 512, 0, stream>>>(hin, xp + (size_t)t * 131072, wp, bias, cbuf,
                                       out + (size_t)t * 131072, hout);
    unsigned short* tmp = hin; hin = hout; hout = tmp;
  }

  // outputs: [S,B,H] | hN | cN
  hipMemcpyAsync(out + (size_t)S_LEN * 131072, out + (size_t)(S_LEN - 1) * 131072,
                 131072 * sizeof(float), hipMemcpyDeviceToDevice, stream);
  hipMemcpyAsync(out + (size_t)S_LEN * 131072 + 131072, cbuf,
                 131072 * sizeof(float), hipMemcpyDeviceToDevice, stream);
}